// Round 1
// 295.483 us; speedup vs baseline: 1.0564x; 1.0564x over previous
//
#include <hip/hip_runtime.h>
#include <hip/hip_bf16.h>

// Problem constants (HyperGCNConv: N=100000, M=50000, K=8, DIN=DOUT=128)
#define NV 100000
#define ME 50000
#define NINC (ME * 8)                     // 400000 incidences
#define NBLK ((NV + 255) / 256)           // 391 scan blocks
constexpr float WMED = 1.0f / 13.0f;      // 1/(2K-3), K=8

typedef __attribute__((ext_vector_type(8))) short bf16x8;   // MFMA A/B frag
typedef __attribute__((ext_vector_type(4))) float f32x4;    // MFMA C/D frag

static __device__ inline void cvt_split8(const float4& a, const float4& b,
                                         bf16x8& hi, bf16x8& lo) {
    const float v[8] = {a.x, a.y, a.z, a.w, b.x, b.y, b.z, b.w};
    #pragma unroll
    for (int j = 0; j < 8; ++j) {
        __hip_bfloat16 h = __float2bfloat16(v[j]);
        const float hf = __bfloat162float(h);
        __hip_bfloat16 l = __float2bfloat16(v[j] - hf);
        union { __hip_bfloat16 b; short s; } uh{h}, ul{l};
        hi[j] = uh.s;
        lo[j] = ul.s;
    }
}

// ---------------- K1: Y = X @ W + b via split-bf16 MFMA ----------------
// 3-term split (Xh·Wh + Xh·Wl + Xl·Wh) -> ~1e-5 relative error (argmax-safe).
// B-frag LDS layout: frag index (s*8+g)*64 + lane  => the 64 lanes of a wave
// read 64 consecutive 16B frags (1024 contiguous bytes) -> conflict-free.
//
// R0 (this session): 512-thread blocks. The 64 KiB W tile in LDS is wave-
// invariant, so share it across 8 waves instead of 4: 2 blocks/CU => 16
// waves/CU (occupancy cap 25% -> 50%), and W stagings halve (782 -> 391).
// Ybf epilogue: lane-pair shfl_xor packs __hip_bfloat162 (4B stores) to cut
// the 2x TCC write amplification of scalar 2B stores.
__global__ __launch_bounds__(512, 4) void k_gemm(const float* __restrict__ X,
                                                 const float* __restrict__ W,
                                                 const float* __restrict__ bias,
                                                 float* __restrict__ Y,
                                                 __hip_bfloat16* __restrict__ Ybf) {
    __shared__ bf16x8 sWh[2048];   // frag (s*8+g)*64 + (q*16+m) -> W[32s+8q+j][16g+m]
    __shared__ bf16x8 sWl[2048];
    const int t = threadIdx.x;
    const int wv = t >> 6;         // wave 0..7 -> rows 32wv..32wv+31
    const int L  = t & 63;
    const int m  = L & 15;         // A row sel / B,C col sel
    const int q  = L >> 4;         // k-quad / C row-quad

    // ---- stage W split into LDS (one-time, all 512 threads) ----
    for (int idx = t; idx < 128 * 32; idx += 512) {
        const int k  = idx >> 5;            // 0..127
        const int c4 = (idx & 31) * 4;      // col group
        const float4 w = *(const float4*)(W + (long)k * 128 + c4);
        const float wv4[4] = {w.x, w.y, w.z, w.w};
        short* swh = (short*)sWh;
        short* swl = (short*)sWl;
        const int s = k >> 5, qq = (k >> 3) & 3, j = k & 7;
        #pragma unroll
        for (int j2 = 0; j2 < 4; ++j2) {
            const int c = c4 + j2;
            const int frag = (s * 8 + (c >> 4)) * 64 + qq * 16 + (c & 15);
            __hip_bfloat16 h = __float2bfloat16(wv4[j2]);
            const float hf = __bfloat162float(h);
            __hip_bfloat16 l = __float2bfloat16(wv4[j2] - hf);
            union { __hip_bfloat16 b; short s; } uh{h}, ul{l};
            swh[frag * 8 + j] = uh.s;
            swl[frag * 8 + j] = ul.s;
        }
    }
    __syncthreads();

    f32x4 acc[2][8];
    #pragma unroll
    for (int tt = 0; tt < 2; ++tt)
        #pragma unroll
        for (int g = 0; g < 8; ++g)
            acc[tt][g] = (f32x4){0.f, 0.f, 0.f, 0.f};

    const int row_base = blockIdx.x * 256 + wv * 32;
    int r0 = row_base + m;      if (r0 > NV - 1) r0 = NV - 1;
    int r1 = row_base + 16 + m; if (r1 > NV - 1) r1 = NV - 1;

    #pragma unroll
    for (int s = 0; s < 4; ++s) {
        const int kb = s * 32 + q * 8;
        const float4 a00 = *(const float4*)(X + (long)r0 * 128 + kb);
        const float4 a01 = *(const float4*)(X + (long)r0 * 128 + kb + 4);
        const float4 a10 = *(const float4*)(X + (long)r1 * 128 + kb);
        const float4 a11 = *(const float4*)(X + (long)r1 * 128 + kb + 4);
        bf16x8 ah0, al0, ah1, al1;
        cvt_split8(a00, a01, ah0, al0);
        cvt_split8(a10, a11, ah1, al1);
        #pragma unroll
        for (int g = 0; g < 8; ++g) {
            const bf16x8 bh = sWh[(s * 8 + g) * 64 + L];
            const bf16x8 bl = sWl[(s * 8 + g) * 64 + L];
            acc[0][g] = __builtin_amdgcn_mfma_f32_16x16x32_bf16(ah0, bh, acc[0][g], 0, 0, 0);
            acc[0][g] = __builtin_amdgcn_mfma_f32_16x16x32_bf16(ah0, bl, acc[0][g], 0, 0, 0);
            acc[0][g] = __builtin_amdgcn_mfma_f32_16x16x32_bf16(al0, bh, acc[0][g], 0, 0, 0);
            acc[1][g] = __builtin_amdgcn_mfma_f32_16x16x32_bf16(ah1, bh, acc[1][g], 0, 0, 0);
            acc[1][g] = __builtin_amdgcn_mfma_f32_16x16x32_bf16(ah1, bl, acc[1][g], 0, 0, 0);
            acc[1][g] = __builtin_amdgcn_mfma_f32_16x16x32_bf16(al1, bh, acc[1][g], 0, 0, 0);
        }
    }

    // epilogue: C layout col=lane&15, row=quad*4+reg
    #pragma unroll
    for (int g = 0; g < 8; ++g) {
        const int col = g * 16 + m;
        const float bc = bias[col];
        #pragma unroll
        for (int tt = 0; tt < 2; ++tt) {
            #pragma unroll
            for (int r = 0; r < 4; ++r) {
                const int row = row_base + tt * 16 + q * 4 + r;
                const float v = acc[tt][g][r] + bc;
                const float vn = __shfl_xor(v, 1);   // neighbor col (lane pair)
                if (row < NV) {
                    Y[(long)row * 128 + col] = v;
                    if ((L & 1) == 0) {              // even lane stores packed pair
                        __hip_bfloat162 h2;
                        h2.x = __float2bfloat16(v);
                        h2.y = __float2bfloat16(vn);
                        *(__hip_bfloat162*)(Ybf + (long)row * 128 + col) = h2;
                    }
                }
            }
        }
    }
}

// ---------------- K2: per-hyperedge argmax pair (uvpos only) ----------------
__global__ __launch_bounds__(256) void k_edge(const float* __restrict__ Y,
                                              const int* __restrict__ vertex,
                                              int* __restrict__ uvpos) {
    __shared__ float sF[4][8 * 132];
    const int wid = threadIdx.x >> 6;
    const int lane = threadIdx.x & 63;
    const int m = blockIdx.x * 4 + wid;
    float* F = sF[wid];

    int verts[8];
    #pragma unroll
    for (int p = 0; p < 8; ++p) verts[p] = vertex[m * 8 + p];

    #pragma unroll
    for (int p = 0; p < 8; ++p) {
        const float2 v = *(const float2*)(Y + (long)verts[p] * 128 + lane * 2);
        *(float2*)(F + p * 132 + lane * 2) = v;
    }
    __syncthreads();

    const int k = lane >> 3, l = lane & 7;
    float acc = 0.0f;
    const float4* ra = (const float4*)(F + k * 132);
    const float4* rb = (const float4*)(F + l * 132);
    #pragma unroll
    for (int d4 = 0; d4 < 32; ++d4) {
        const float4 a = ra[d4], b = rb[d4];
        acc = fmaf(a.x, b.x, acc);
        acc = fmaf(a.y, b.y, acc);
        acc = fmaf(a.z, b.z, acc);
        acc = fmaf(a.w, b.w, acc);
    }
    const float sqk = __shfl(acc, k * 9);
    const float sql = __shfl(acc, l * 9);
    float v = sqk + sql - 2.0f * acc;
    int idx = lane;
    #pragma unroll
    for (int off = 32; off >= 1; off >>= 1) {
        const float ov = __shfl_xor(v, off);
        const int oi = __shfl_xor(idx, off);
        if (ov > v || (ov == v && oi < idx)) { v = ov; idx = oi; }
    }
    if (lane == 0) uvpos[m] = idx;
}

// ---------------- K2a: init cnt=0, rowptr[NV]=NINC ----------------
__global__ __launch_bounds__(256) void k_init(int* __restrict__ cnt,
                                              int* __restrict__ rowptr) {
    const int i = blockIdx.x * 256 + threadIdx.x;
    if (i < NV) cnt[i] = 0;
    if (i == 0) rowptr[NV] = NINC;
}

// ---------------- CSR build: histogram ----------------
__global__ __launch_bounds__(256) void k_hist(const int* __restrict__ vertex,
                                              int* __restrict__ cnt) {
    const int j = blockIdx.x * 256 + threadIdx.x;
    if (j < NINC) atomicAdd(cnt + vertex[j], 1);
}

// ---------------- CSR build: scan stage 1 (per-block sums) ----------------
__global__ __launch_bounds__(256) void k_scan1(const int* __restrict__ cnt,
                                               int* __restrict__ bsum) {
    __shared__ int s[256];
    const int t = threadIdx.x;
    const int i = blockIdx.x * 256 + t;
    s[t] = (i < NV) ? cnt[i] : 0;
    __syncthreads();
    #pragma unroll
    for (int off = 128; off >= 1; off >>= 1) {
        if (t < off) s[t] += s[t + off];
        __syncthreads();
    }
    if (t == 0) bsum[blockIdx.x] = s[0];
}

// ---------------- CSR build: scan stage 2 (exclusive scan of block sums) ---
__global__ __launch_bounds__(64) void k_scan2(const int* __restrict__ bsum,
                                              int* __restrict__ boff) {
    const int lane = threadIdx.x;   // single wave
    int running = 0;
    for (int c = 0; c * 64 < NBLK; ++c) {
        const int idx = c * 64 + lane;
        int v = (idx < NBLK) ? bsum[idx] : 0;
        int x = v;
        #pragma unroll
        for (int off = 1; off < 64; off <<= 1) {
            const int n = __shfl_up(x, off);
            if (lane >= off) x += n;
        }
        if (idx < NBLK) boff[idx] = running + x - v;   // exclusive
        running += __shfl(x, 63);
    }
}

// ---------------- CSR build: scan stage 3 (rowptr + fill ptr) ----------------
__global__ __launch_bounds__(256) void k_scan3(const int* __restrict__ cnt,
                                               const int* __restrict__ boff,
                                               int* __restrict__ rowptr,
                                               int* __restrict__ fill) {
    __shared__ int s[256];
    const int t = threadIdx.x;
    const int i = blockIdx.x * 256 + t;
    const int v = (i < NV) ? cnt[i] : 0;
    s[t] = v;
    __syncthreads();
    #pragma unroll
    for (int off = 1; off < 256; off <<= 1) {
        const int add = (t >= off) ? s[t - off] : 0;
        __syncthreads();
        s[t] += add;
        __syncthreads();
    }
    if (i < NV) {
        const int excl = boff[blockIdx.x] + s[t] - v;
        rowptr[i] = excl;
        fill[i] = excl;
    }
}

// ---------------- CSR build: fill entries with (m<<1)|role ----------------
__global__ __launch_bounds__(256) void k_fill(const int* __restrict__ vertex,
                                              const int* __restrict__ uvpos,
                                              int* __restrict__ fill,
                                              int* __restrict__ entries) {
    const int j = blockIdx.x * 256 + threadIdx.x;
    if (j < NINC) {
        const int v = vertex[j];
        const int m = j >> 3, p = j & 7;
        const int idx = uvpos[m];
        const int role = (p == (idx >> 3) || p == (idx & 7)) ? 0 : 1;
        const int slot = atomicAdd(fill + v, 1);
        entries[slot] = (m << 1) | role;
    }
}

// ---------------- K3: exact per-vertex degree (no atomics) ----------------
__global__ __launch_bounds__(256) void k_deg(const int* __restrict__ rowptr,
                                             const int* __restrict__ entries,
                                             float* __restrict__ deg) {
    const int i = blockIdx.x * 256 + threadIdx.x;
    if (i >= NV) return;
    const int start = rowptr[i], end = rowptr[i + 1];
    float d = 1.0f;
    for (int e = start; e < end; ++e)
        d += (entries[e] & 1) ? (2.0f * WMED) : (7.0f * WMED);
    deg[i] = d;
}

// ---------------- K4: per-edge w*S, w*P rows (reads bf16 Y copy) ----------
__global__ __launch_bounds__(256) void k_sp(const __hip_bfloat16* __restrict__ Ybf,
                                            const int* __restrict__ vertex,
                                            const int* __restrict__ uvpos,
                                            const float* __restrict__ deg,
                                            __hip_bfloat162* __restrict__ SP) {
    const int wid = threadIdx.x >> 6;
    const int lane = threadIdx.x & 63;
    const int m = blockIdx.x * 4 + wid;

    const int idx = uvpos[m];
    const int ui = idx >> 3, vi = idx & 7;

    float S0 = 0.f, S1 = 0.f, U0 = 0.f, U1 = 0.f, V0 = 0.f, V1 = 0.f;
    #pragma unroll
    for (int p = 0; p < 8; ++p) {
        const int vp = vertex[m * 8 + p];
        const float di = rsqrtf(deg[vp]);
        const __hip_bfloat162 y2 =
            ((const __hip_bfloat162*)(Ybf + (long)vp * 128))[lane];
        const float r0 = __bfloat162float(y2.x) * di;
        const float r1 = __bfloat162float(y2.y) * di;
        S0 += r0; S1 += r1;
        if (p == ui) { U0 = r0; U1 = r1; }
        if (p == vi) { V0 = r0; V1 = r1; }
    }
    __hip_bfloat162 s2, p2;
    s2.x = __float2bfloat16(WMED * S0);
    s2.y = __float2bfloat16(WMED * S1);
    p2.x = __float2bfloat16(WMED * (U0 + V0));
    p2.y = __float2bfloat16(WMED * (U1 + V1));
    SP[(long)(2 * m) * 64 + lane] = s2;        // S row
    SP[(long)(2 * m + 1) * 64 + lane] = p2;    // P row
}

// ---------------- K5: per-vertex gather: one bf16 row per incidence --------
__global__ __launch_bounds__(256) void k_gather(const float* __restrict__ Y,
                                                const float* __restrict__ deg,
                                                const int* __restrict__ rowptr,
                                                const int* __restrict__ entries,
                                                const __hip_bfloat162* __restrict__ SP,
                                                float* __restrict__ out) {
    const int wid = threadIdx.x >> 6;
    const int lane = threadIdx.x & 63;
    const int i = blockIdx.x * 4 + wid;

    const float din = rsqrtf(deg[i]);
    const float2 y = *(const float2*)(Y + (long)i * 128 + lane * 2);
    const float xs0 = y.x * din;
    const float xs1 = y.y * din;

    float a0 = 0.f, a1 = 0.f;
    int nuv = 0;
    const int start = rowptr[i], end = rowptr[i + 1];
    for (int e = start; e < end; ++e) {
        const int t = entries[e];
        nuv += (t & 1) ^ 1;
        const __hip_bfloat162 T = SP[(long)t * 64 + lane];
        a0 += __bfloat162float(T.x);
        a1 += __bfloat162float(T.y);
    }
    const float self = 1.0f - WMED * (float)nuv;
    a0 = fmaf(self, xs0, a0);
    a1 = fmaf(self, xs1, a1);
    float2 o;
    o.x = fmaxf(a0 * din, 0.0f);
    o.y = fmaxf(a1 * din, 0.0f);
    *(float2*)(out + (long)i * 128 + lane * 2) = o;
}

extern "C" void kernel_launch(void* const* d_in, const int* in_sizes, int n_in,
                              void* d_out, int out_size, void* d_ws, size_t ws_size,
                              hipStream_t stream) {
    const float* X      = (const float*)d_in[0];   // [N,128]
    const int*   vertex = (const int*)d_in[1];     // [M*8]
    // d_in[2] = edges (repeat(arange(M),8)) -- unused
    const float* W      = (const float*)d_in[3];   // [128,128]
    const float* bias   = (const float*)d_in[4];   // [128]
    float* out = (float*)d_out;                    // [N,128]

    // workspace: Y[N*128] f32 | Ybf[N*128] bf16 | SP[2M*128] bf16 | deg[N] |
    //            uvpos[M] | cnt[N] | rowptr[N+1] | fill[N] | bsum | boff | entries
    float* Y              = (float*)d_ws;
    __hip_bfloat16* Ybf   = (__hip_bfloat16*)(Y + (long)NV * 128);
    __hip_bfloat162* SP   = (__hip_bfloat162*)(Ybf + (long)NV * 128);
    float* deg            = (float*)((__hip_bfloat16*)SP + (long)2 * ME * 128);
    int*   uvpos          = (int*)(deg + NV);
    int*   cnt            = uvpos + ME;
    int*   rowptr         = cnt + NV;
    int*   fill           = rowptr + NV + 1;
    int*   bsum           = fill + NV;
    int*   boff           = bsum + NBLK;
    int*   entries        = boff + NBLK;

    k_gemm <<<(NV + 255) / 256, 512, 0, stream>>>(X, W, bias, Y, Ybf);
    k_edge <<<ME / 4, 256, 0, stream>>>(Y, vertex, uvpos);
    k_init <<<NBLK, 256, 0, stream>>>(cnt, rowptr);
    k_hist <<<(NINC + 255) / 256, 256, 0, stream>>>(vertex, cnt);
    k_scan1<<<NBLK, 256, 0, stream>>>(cnt, bsum);
    k_scan2<<<1, 64, 0, stream>>>(bsum, boff);
    k_scan3<<<NBLK, 256, 0, stream>>>(cnt, boff, rowptr, fill);
    k_fill <<<(NINC + 255) / 256, 256, 0, stream>>>(vertex, uvpos, fill, entries);
    k_deg  <<<NBLK, 256, 0, stream>>>(rowptr, entries, deg);
    k_sp   <<<ME / 4, 256, 0, stream>>>(Ybf, vertex, uvpos, deg, SP);
    k_gather<<<NV / 4, 256, 0, stream>>>(Y, deg, rowptr, entries, SP, out);
}

// Round 2
// 276.829 us; speedup vs baseline: 1.1276x; 1.0674x over previous
//
#include <hip/hip_runtime.h>
#include <hip/hip_bf16.h>

// Problem constants (HyperGCNConv: N=100000, M=50000, K=8, DIN=DOUT=128)
#define NV 100000
#define ME 50000
#define NINC (ME * 8)                     // 400000 incidences
#define NBLK ((NV + 255) / 256)           // 391 scan blocks
constexpr float WMED = 1.0f / 13.0f;      // 1/(2K-3), K=8

typedef __attribute__((ext_vector_type(8))) short bf16x8;   // MFMA A/B frag
typedef __attribute__((ext_vector_type(4))) float f32x4;    // MFMA C/D frag

static __device__ inline void cvt_split8(const float4& a, const float4& b,
                                         bf16x8& hi, bf16x8& lo) {
    const float v[8] = {a.x, a.y, a.z, a.w, b.x, b.y, b.z, b.w};
    #pragma unroll
    for (int j = 0; j < 8; ++j) {
        __hip_bfloat16 h = __float2bfloat16(v[j]);
        const float hf = __bfloat162float(h);
        __hip_bfloat16 l = __float2bfloat16(v[j] - hf);
        union { __hip_bfloat16 b; short s; } uh{h}, ul{l};
        hi[j] = uh.s;
        lo[j] = ul.s;
    }
}

// ---------------- K1: Y = X @ W + b via split-bf16 MFMA ----------------
// 3-term split (Xh·Wh + Xh·Wl + Xl·Wh) -> ~1e-5 relative error (argmax-safe).
// B-frag LDS layout: frag index (s*8+g)*64 + lane  => the 64 lanes of a wave
// read 64 consecutive 16B frags (1024 contiguous bytes) -> conflict-free.
//
// R0: 512-thread blocks. The 64 KiB W tile in LDS is wave-invariant, so share
// it across 8 waves: 2 blocks/CU => 16 waves/CU, W stagings halve.
// Ybf epilogue: lane-pair shfl_xor packs __hip_bfloat162 (4B stores).
__global__ __launch_bounds__(512, 4) void k_gemm(const float* __restrict__ X,
                                                 const float* __restrict__ W,
                                                 const float* __restrict__ bias,
                                                 float* __restrict__ Y,
                                                 __hip_bfloat16* __restrict__ Ybf) {
    __shared__ bf16x8 sWh[2048];   // frag (s*8+g)*64 + (q*16+m) -> W[32s+8q+j][16g+m]
    __shared__ bf16x8 sWl[2048];
    const int t = threadIdx.x;
    const int wv = t >> 6;         // wave 0..7 -> rows 32wv..32wv+31
    const int L  = t & 63;
    const int m  = L & 15;         // A row sel / B,C col sel
    const int q  = L >> 4;         // k-quad / C row-quad

    // ---- stage W split into LDS (one-time, all 512 threads) ----
    for (int idx = t; idx < 128 * 32; idx += 512) {
        const int k  = idx >> 5;            // 0..127
        const int c4 = (idx & 31) * 4;      // col group
        const float4 w = *(const float4*)(W + (long)k * 128 + c4);
        const float wv4[4] = {w.x, w.y, w.z, w.w};
        short* swh = (short*)sWh;
        short* swl = (short*)sWl;
        const int s = k >> 5, qq = (k >> 3) & 3, j = k & 7;
        #pragma unroll
        for (int j2 = 0; j2 < 4; ++j2) {
            const int c = c4 + j2;
            const int frag = (s * 8 + (c >> 4)) * 64 + qq * 16 + (c & 15);
            __hip_bfloat16 h = __float2bfloat16(wv4[j2]);
            const float hf = __bfloat162float(h);
            __hip_bfloat16 l = __float2bfloat16(wv4[j2] - hf);
            union { __hip_bfloat16 b; short s; } uh{h}, ul{l};
            swh[frag * 8 + j] = uh.s;
            swl[frag * 8 + j] = ul.s;
        }
    }
    __syncthreads();

    f32x4 acc[2][8];
    #pragma unroll
    for (int tt = 0; tt < 2; ++tt)
        #pragma unroll
        for (int g = 0; g < 8; ++g)
            acc[tt][g] = (f32x4){0.f, 0.f, 0.f, 0.f};

    const int row_base = blockIdx.x * 256 + wv * 32;
    int r0 = row_base + m;      if (r0 > NV - 1) r0 = NV - 1;
    int r1 = row_base + 16 + m; if (r1 > NV - 1) r1 = NV - 1;

    #pragma unroll
    for (int s = 0; s < 4; ++s) {
        const int kb = s * 32 + q * 8;
        const float4 a00 = *(const float4*)(X + (long)r0 * 128 + kb);
        const float4 a01 = *(const float4*)(X + (long)r0 * 128 + kb + 4);
        const float4 a10 = *(const float4*)(X + (long)r1 * 128 + kb);
        const float4 a11 = *(const float4*)(X + (long)r1 * 128 + kb + 4);
        bf16x8 ah0, al0, ah1, al1;
        cvt_split8(a00, a01, ah0, al0);
        cvt_split8(a10, a11, ah1, al1);
        #pragma unroll
        for (int g = 0; g < 8; ++g) {
            const bf16x8 bh = sWh[(s * 8 + g) * 64 + L];
            const bf16x8 bl = sWl[(s * 8 + g) * 64 + L];
            acc[0][g] = __builtin_amdgcn_mfma_f32_16x16x32_bf16(ah0, bh, acc[0][g], 0, 0, 0);
            acc[0][g] = __builtin_amdgcn_mfma_f32_16x16x32_bf16(ah0, bl, acc[0][g], 0, 0, 0);
            acc[0][g] = __builtin_amdgcn_mfma_f32_16x16x32_bf16(al0, bh, acc[0][g], 0, 0, 0);
            acc[1][g] = __builtin_amdgcn_mfma_f32_16x16x32_bf16(ah1, bh, acc[1][g], 0, 0, 0);
            acc[1][g] = __builtin_amdgcn_mfma_f32_16x16x32_bf16(ah1, bl, acc[1][g], 0, 0, 0);
            acc[1][g] = __builtin_amdgcn_mfma_f32_16x16x32_bf16(al1, bh, acc[1][g], 0, 0, 0);
        }
    }

    // epilogue: C layout col=lane&15, row=quad*4+reg
    #pragma unroll
    for (int g = 0; g < 8; ++g) {
        const int col = g * 16 + m;
        const float bc = bias[col];
        #pragma unroll
        for (int tt = 0; tt < 2; ++tt) {
            #pragma unroll
            for (int r = 0; r < 4; ++r) {
                const int row = row_base + tt * 16 + q * 4 + r;
                const float v = acc[tt][g][r] + bc;
                const float vn = __shfl_xor(v, 1);   // neighbor col (lane pair)
                if (row < NV) {
                    Y[(long)row * 128 + col] = v;
                    if ((L & 1) == 0) {              // even lane stores packed pair
                        __hip_bfloat162 h2;
                        h2.x = __float2bfloat16(v);
                        h2.y = __float2bfloat16(vn);
                        *(__hip_bfloat162*)(Ybf + (long)row * 128 + col) = h2;
                    }
                }
            }
        }
    }
}

// ---------------- K2: per-hyperedge argmax pair (uvpos only) ----------------
__global__ __launch_bounds__(256) void k_edge(const float* __restrict__ Y,
                                              const int* __restrict__ vertex,
                                              int* __restrict__ uvpos) {
    __shared__ float sF[4][8 * 132];
    const int wid = threadIdx.x >> 6;
    const int lane = threadIdx.x & 63;
    const int m = blockIdx.x * 4 + wid;
    float* F = sF[wid];

    int verts[8];
    #pragma unroll
    for (int p = 0; p < 8; ++p) verts[p] = vertex[m * 8 + p];

    #pragma unroll
    for (int p = 0; p < 8; ++p) {
        const float2 v = *(const float2*)(Y + (long)verts[p] * 128 + lane * 2);
        *(float2*)(F + p * 132 + lane * 2) = v;
    }
    __syncthreads();

    const int k = lane >> 3, l = lane & 7;
    float acc = 0.0f;
    const float4* ra = (const float4*)(F + k * 132);
    const float4* rb = (const float4*)(F + l * 132);
    #pragma unroll
    for (int d4 = 0; d4 < 32; ++d4) {
        const float4 a = ra[d4], b = rb[d4];
        acc = fmaf(a.x, b.x, acc);
        acc = fmaf(a.y, b.y, acc);
        acc = fmaf(a.z, b.z, acc);
        acc = fmaf(a.w, b.w, acc);
    }
    const float sqk = __shfl(acc, k * 9);
    const float sql = __shfl(acc, l * 9);
    float v = sqk + sql - 2.0f * acc;
    int idx = lane;
    #pragma unroll
    for (int off = 32; off >= 1; off >>= 1) {
        const float ov = __shfl_xor(v, off);
        const int oi = __shfl_xor(idx, off);
        if (ov > v || (ov == v && oi < idx)) { v = ov; idx = oi; }
    }
    if (lane == 0) uvpos[m] = idx;
}

// ---------------- K2a: init cnt=0, rowptr[NV]=NINC ----------------
__global__ __launch_bounds__(256) void k_init(int* __restrict__ cnt,
                                              int* __restrict__ rowptr) {
    const int i = blockIdx.x * 256 + threadIdx.x;
    if (i < NV) cnt[i] = 0;
    if (i == 0) rowptr[NV] = NINC;
}

// ---------------- CSR build: histogram ----------------
__global__ __launch_bounds__(256) void k_hist(const int* __restrict__ vertex,
                                              int* __restrict__ cnt) {
    const int j = blockIdx.x * 256 + threadIdx.x;
    if (j < NINC) atomicAdd(cnt + vertex[j], 1);
}

// ---------------- CSR build: scan stage 1 (per-block sums) ----------------
__global__ __launch_bounds__(256) void k_scan1(const int* __restrict__ cnt,
                                               int* __restrict__ bsum) {
    __shared__ int s[256];
    const int t = threadIdx.x;
    const int i = blockIdx.x * 256 + t;
    s[t] = (i < NV) ? cnt[i] : 0;
    __syncthreads();
    #pragma unroll
    for (int off = 128; off >= 1; off >>= 1) {
        if (t < off) s[t] += s[t + off];
        __syncthreads();
    }
    if (t == 0) bsum[blockIdx.x] = s[0];
}

// ---------------- CSR build: scan stage 2 (exclusive scan of block sums) ---
__global__ __launch_bounds__(64) void k_scan2(const int* __restrict__ bsum,
                                              int* __restrict__ boff) {
    const int lane = threadIdx.x;   // single wave
    int running = 0;
    for (int c = 0; c * 64 < NBLK; ++c) {
        const int idx = c * 64 + lane;
        int v = (idx < NBLK) ? bsum[idx] : 0;
        int x = v;
        #pragma unroll
        for (int off = 1; off < 64; off <<= 1) {
            const int n = __shfl_up(x, off);
            if (lane >= off) x += n;
        }
        if (idx < NBLK) boff[idx] = running + x - v;   // exclusive
        running += __shfl(x, 63);
    }
}

// ---------------- CSR build: scan stage 3 (rowptr + fill ptr) ----------------
__global__ __launch_bounds__(256) void k_scan3(const int* __restrict__ cnt,
                                               const int* __restrict__ boff,
                                               int* __restrict__ rowptr,
                                               int* __restrict__ fill) {
    __shared__ int s[256];
    const int t = threadIdx.x;
    const int i = blockIdx.x * 256 + t;
    const int v = (i < NV) ? cnt[i] : 0;
    s[t] = v;
    __syncthreads();
    #pragma unroll
    for (int off = 1; off < 256; off <<= 1) {
        const int add = (t >= off) ? s[t - off] : 0;
        __syncthreads();
        s[t] += add;
        __syncthreads();
    }
    if (i < NV) {
        const int excl = boff[blockIdx.x] + s[t] - v;
        rowptr[i] = excl;
        fill[i] = excl;
    }
}

// ---------------- CSR build: fill entries with (m<<1)|role ----------------
__global__ __launch_bounds__(256) void k_fill(const int* __restrict__ vertex,
                                              const int* __restrict__ uvpos,
                                              int* __restrict__ fill,
                                              int* __restrict__ entries) {
    const int j = blockIdx.x * 256 + threadIdx.x;
    if (j < NINC) {
        const int v = vertex[j];
        const int m = j >> 3, p = j & 7;
        const int idx = uvpos[m];
        const int role = (p == (idx >> 3) || p == (idx & 7)) ? 0 : 1;
        const int slot = atomicAdd(fill + v, 1);
        entries[slot] = (m << 1) | role;
    }
}

// ---------------- K3: exact per-vertex degree (no atomics) ----------------
__global__ __launch_bounds__(256) void k_deg(const int* __restrict__ rowptr,
                                             const int* __restrict__ entries,
                                             float* __restrict__ deg) {
    const int i = blockIdx.x * 256 + threadIdx.x;
    if (i >= NV) return;
    const int start = rowptr[i], end = rowptr[i + 1];
    float d = 1.0f;
    for (int e = start; e < end; ++e)
        d += (entries[e] & 1) ? (2.0f * WMED) : (7.0f * WMED);
    deg[i] = d;
}

// ---------------- K4: per-edge w*S, w*P rows (reads bf16 Y copy) ----------
__global__ __launch_bounds__(256) void k_sp(const __hip_bfloat16* __restrict__ Ybf,
                                            const int* __restrict__ vertex,
                                            const int* __restrict__ uvpos,
                                            const float* __restrict__ deg,
                                            __hip_bfloat162* __restrict__ SP) {
    const int wid = threadIdx.x >> 6;
    const int lane = threadIdx.x & 63;
    const int m = blockIdx.x * 4 + wid;

    const int idx = uvpos[m];
    const int ui = idx >> 3, vi = idx & 7;

    float S0 = 0.f, S1 = 0.f, U0 = 0.f, U1 = 0.f, V0 = 0.f, V1 = 0.f;
    #pragma unroll
    for (int p = 0; p < 8; ++p) {
        const int vp = vertex[m * 8 + p];
        const float di = rsqrtf(deg[vp]);
        const __hip_bfloat162 y2 =
            ((const __hip_bfloat162*)(Ybf + (long)vp * 128))[lane];
        const float r0 = __bfloat162float(y2.x) * di;
        const float r1 = __bfloat162float(y2.y) * di;
        S0 += r0; S1 += r1;
        if (p == ui) { U0 = r0; U1 = r1; }
        if (p == vi) { V0 = r0; V1 = r1; }
    }
    __hip_bfloat162 s2, p2;
    s2.x = __float2bfloat16(WMED * S0);
    s2.y = __float2bfloat16(WMED * S1);
    p2.x = __float2bfloat16(WMED * (U0 + V0));
    p2.y = __float2bfloat16(WMED * (U1 + V1));
    SP[(long)(2 * m) * 64 + lane] = s2;        // S row
    SP[(long)(2 * m + 1) * 64 + lane] = p2;    // P row
}

// ---------------- K5: per-vertex gather: one bf16 row per incidence --------
// R1: latency-bound fix. The old loop serialized (entries[e] -> SP[t]) per
// iteration (~8 dependent latencies at avg deg=4). Now: ONE lane-indexed load
// fetches the whole entry row (deg<=64 covers all but pathological rows),
// t's come from cheap __shfl, and SP rows load 4-wide independent per chunk
// (masked-duplicate remainder keeps the loads straight-line).
__global__ __launch_bounds__(256) void k_gather(const float* __restrict__ Y,
                                                const float* __restrict__ deg,
                                                const int* __restrict__ rowptr,
                                                const int* __restrict__ entries,
                                                const __hip_bfloat162* __restrict__ SP,
                                                float* __restrict__ out) {
    const int wid = threadIdx.x >> 6;
    const int lane = threadIdx.x & 63;
    const int i = blockIdx.x * 4 + wid;

    const int start = rowptr[i], end = rowptr[i + 1];
    const int degc = end - start;
    // one coalesced load grabs all entries of this row
    const int tl = (lane < degc) ? entries[start + lane] : 0;

    const float din = rsqrtf(deg[i]);
    const float2 y = *(const float2*)(Y + (long)i * 128 + lane * 2);
    const float xs0 = y.x * din;
    const float xs1 = y.y * din;

    float a0 = 0.f, a1 = 0.f;
    float fnuv = 0.f;
    const int dmain = (degc < 64) ? degc : 64;

    for (int e = 0; e < dmain; e += 4) {
        const int j1 = (e + 1 < dmain) ? e + 1 : e;
        const int j2 = (e + 2 < dmain) ? e + 2 : e;
        const int j3 = (e + 3 < dmain) ? e + 3 : e;
        const float m1 = (e + 1 < dmain) ? 1.f : 0.f;
        const float m2 = (e + 2 < dmain) ? 1.f : 0.f;
        const float m3 = (e + 3 < dmain) ? 1.f : 0.f;
        const int t0 = __shfl(tl, e);
        const int t1 = __shfl(tl, j1);
        const int t2 = __shfl(tl, j2);
        const int t3 = __shfl(tl, j3);
        // 4 independent 256B row loads issue back-to-back
        const __hip_bfloat162 T0 = SP[(long)t0 * 64 + lane];
        const __hip_bfloat162 T1 = SP[(long)t1 * 64 + lane];
        const __hip_bfloat162 T2 = SP[(long)t2 * 64 + lane];
        const __hip_bfloat162 T3 = SP[(long)t3 * 64 + lane];
        fnuv += (float)((t0 & 1) ^ 1) + m1 * (float)((t1 & 1) ^ 1)
              + m2 * (float)((t2 & 1) ^ 1) + m3 * (float)((t3 & 1) ^ 1);
        a0 += __bfloat162float(T0.x) + m1 * __bfloat162float(T1.x)
            + m2 * __bfloat162float(T2.x) + m3 * __bfloat162float(T3.x);
        a1 += __bfloat162float(T0.y) + m1 * __bfloat162float(T1.y)
            + m2 * __bfloat162float(T2.y) + m3 * __bfloat162float(T3.y);
    }
    // pathological overflow (deg > 64): serial fallback, essentially never taken
    for (int e2 = start + 64; e2 < end; ++e2) {
        const int t = entries[e2];
        const __hip_bfloat162 T = SP[(long)t * 64 + lane];
        fnuv += (float)((t & 1) ^ 1);
        a0 += __bfloat162float(T.x);
        a1 += __bfloat162float(T.y);
    }

    const float self = 1.0f - WMED * fnuv;
    a0 = fmaf(self, xs0, a0);
    a1 = fmaf(self, xs1, a1);
    float2 o;
    o.x = fmaxf(a0 * din, 0.0f);
    o.y = fmaxf(a1 * din, 0.0f);
    *(float2*)(out + (long)i * 128 + lane * 2) = o;
}

extern "C" void kernel_launch(void* const* d_in, const int* in_sizes, int n_in,
                              void* d_out, int out_size, void* d_ws, size_t ws_size,
                              hipStream_t stream) {
    const float* X      = (const float*)d_in[0];   // [N,128]
    const int*   vertex = (const int*)d_in[1];     // [M*8]
    // d_in[2] = edges (repeat(arange(M),8)) -- unused
    const float* W      = (const float*)d_in[3];   // [128,128]
    const float* bias   = (const float*)d_in[4];   // [128]
    float* out = (float*)d_out;                    // [N,128]

    // workspace: Y[N*128] f32 | Ybf[N*128] bf16 | SP[2M*128] bf16 | deg[N] |
    //            uvpos[M] | cnt[N] | rowptr[N+1] | fill[N] | bsum | boff | entries
    float* Y              = (float*)d_ws;
    __hip_bfloat16* Ybf   = (__hip_bfloat16*)(Y + (long)NV * 128);
    __hip_bfloat162* SP   = (__hip_bfloat162*)(Ybf + (long)NV * 128);
    float* deg            = (float*)((__hip_bfloat16*)SP + (long)2 * ME * 128);
    int*   uvpos          = (int*)(deg + NV);
    int*   cnt            = uvpos + ME;
    int*   rowptr         = cnt + NV;
    int*   fill           = rowptr + NV + 1;
    int*   bsum           = fill + NV;
    int*   boff           = bsum + NBLK;
    int*   entries        = boff + NBLK;

    k_gemm <<<(NV + 255) / 256, 512, 0, stream>>>(X, W, bias, Y, Ybf);
    k_edge <<<ME / 4, 256, 0, stream>>>(Y, vertex, uvpos);
    k_init <<<NBLK, 256, 0, stream>>>(cnt, rowptr);
    k_hist <<<(NINC + 255) / 256, 256, 0, stream>>>(vertex, cnt);
    k_scan1<<<NBLK, 256, 0, stream>>>(cnt, bsum);
    k_scan2<<<1, 64, 0, stream>>>(bsum, boff);
    k_scan3<<<NBLK, 256, 0, stream>>>(cnt, boff, rowptr, fill);
    k_fill <<<(NINC + 255) / 256, 256, 0, stream>>>(vertex, uvpos, fill, entries);
    k_deg  <<<NBLK, 256, 0, stream>>>(rowptr, entries, deg);
    k_sp   <<<ME / 4, 256, 0, stream>>>(Ybf, vertex, uvpos, deg, SP);
    k_gather<<<NV / 4, 256, 0, stream>>>(Y, deg, rowptr, entries, SP, out);
}

// Round 3
// 272.004 us; speedup vs baseline: 1.1476x; 1.0177x over previous
//
#include <hip/hip_runtime.h>
#include <hip/hip_bf16.h>

// Problem constants (HyperGCNConv: N=100000, M=50000, K=8, DIN=DOUT=128)
#define NV 100000
#define ME 50000
#define NINC (ME * 8)                     // 400000 incidences
#define NBLK ((NV + 255) / 256)           // 391 scan blocks
constexpr float WMED = 1.0f / 13.0f;      // 1/(2K-3), K=8

typedef __attribute__((ext_vector_type(8))) short bf16x8;   // MFMA A/B frag
typedef __attribute__((ext_vector_type(4))) float f32x4;    // MFMA C/D frag

static __device__ inline void cvt_split8(const float4& a, const float4& b,
                                         bf16x8& hi, bf16x8& lo) {
    const float v[8] = {a.x, a.y, a.z, a.w, b.x, b.y, b.z, b.w};
    #pragma unroll
    for (int j = 0; j < 8; ++j) {
        __hip_bfloat16 h = __float2bfloat16(v[j]);
        const float hf = __bfloat162float(h);
        __hip_bfloat16 l = __float2bfloat16(v[j] - hf);
        union { __hip_bfloat16 b; short s; } uh{h}, ul{l};
        hi[j] = uh.s;
        lo[j] = ul.s;
    }
}

// ---------------- K0: one-off W split into frag-layout global buffer -------
// Wg frag index = mat*2048 + cb*1024 + (s*4+gp)*64 + (qq*16 + m); 16B frags.
// (mat: 0=Wh 1=Wl; cb: col-block 0/1; element j of frag holds W[32s+8qq+j][...])
__global__ __launch_bounds__(256) void k_wsplit(const float* __restrict__ W,
                                                short* __restrict__ Wg) {
    const int idx = blockIdx.x * 256 + threadIdx.x;   // 16384 elems
    const int k = idx >> 7;          // row 0..127
    const int c = idx & 127;         // col 0..127
    const float w = W[idx];
    __hip_bfloat16 h = __float2bfloat16(w);
    const float hf = __bfloat162float(h);
    __hip_bfloat16 l = __float2bfloat16(w - hf);
    const int cb = c >> 6, gp = (c >> 4) & 3, m = c & 15;
    const int s = k >> 5, qq = (k >> 3) & 3, j = k & 7;
    const int base = cb * 1024 + (s * 4 + gp) * 64 + qq * 16 + m;
    union { __hip_bfloat16 b; short s; } uh{h}, ul{l};
    Wg[(long)base * 8 + j] = uh.s;                    // mat 0 (Wh)
    Wg[(long)(2048 + base) * 8 + j] = ul.s;           // mat 1 (Wl)
}

// ---------------- K1: Y = X @ W + b via split-bf16 MFMA ----------------
// 3-term split (Xh·Wh + Xh·Wl + Xl·Wh) -> ~1e-5 relative error (argmax-safe).
// R2: column-split 2-way. Each block: 256 rows x 64 cols, 32 KiB LDS (half
// the W frags), grid 782 (~3 blocks/CU, 4 allowed by LDS) -> occupancy cap
// 75-100% instead of 25-50%. W is staged by a LINEAR 16B copy from the
// pre-split Wg buffer (k_wsplit): no cvt, no scattered 2B LDS writes, no
// bank conflicts. X re-read 2x is L3-served.
__global__ __launch_bounds__(512, 6) void k_gemm(const float* __restrict__ X,
                                                 const uint4* __restrict__ Wg,
                                                 const float* __restrict__ bias,
                                                 float* __restrict__ Y,
                                                 __hip_bfloat16* __restrict__ Ybf) {
    __shared__ uint4 sW[2048];     // [mat][ (s*4+gp)*64 + L ], 32 KiB
    const int t = threadIdx.x;
    const int wv = t >> 6;         // wave 0..7 -> rows 32wv..32wv+31
    const int L  = t & 63;
    const int m  = L & 15;         // A row sel / B,C col sel
    const int q  = L >> 4;         // k-quad / C row-quad

    const int rb = blockIdx.x >> 1;       // row block (256 rows)
    const int cb = blockIdx.x & 1;        // col block (64 cols)

    // ---- stage pre-split W frags: linear, coalesced, conflict-free ----
    #pragma unroll
    for (int f = 0; f < 4; ++f) {
        const int fi = f * 512 + t;                   // 0..2047
        const int mat = fi >> 10, loc = fi & 1023;
        sW[fi] = Wg[(long)mat * 2048 + cb * 1024 + loc];
    }
    __syncthreads();

    const bf16x8* sWf = (const bf16x8*)sW;

    f32x4 acc[2][4];
    #pragma unroll
    for (int tt = 0; tt < 2; ++tt)
        #pragma unroll
        for (int g = 0; g < 4; ++g)
            acc[tt][g] = (f32x4){0.f, 0.f, 0.f, 0.f};

    const int row_base = rb * 256 + wv * 32;
    int r0 = row_base + m;      if (r0 > NV - 1) r0 = NV - 1;
    int r1 = row_base + 16 + m; if (r1 > NV - 1) r1 = NV - 1;

    #pragma unroll
    for (int s = 0; s < 4; ++s) {
        const int kb = s * 32 + q * 8;
        const float4 a00 = *(const float4*)(X + (long)r0 * 128 + kb);
        const float4 a01 = *(const float4*)(X + (long)r0 * 128 + kb + 4);
        const float4 a10 = *(const float4*)(X + (long)r1 * 128 + kb);
        const float4 a11 = *(const float4*)(X + (long)r1 * 128 + kb + 4);
        bf16x8 ah0, al0, ah1, al1;
        cvt_split8(a00, a01, ah0, al0);
        cvt_split8(a10, a11, ah1, al1);
        #pragma unroll
        for (int g = 0; g < 4; ++g) {
            const bf16x8 bh = sWf[(s * 4 + g) * 64 + L];
            const bf16x8 bl = sWf[1024 + (s * 4 + g) * 64 + L];
            acc[0][g] = __builtin_amdgcn_mfma_f32_16x16x32_bf16(ah0, bh, acc[0][g], 0, 0, 0);
            acc[0][g] = __builtin_amdgcn_mfma_f32_16x16x32_bf16(ah0, bl, acc[0][g], 0, 0, 0);
            acc[0][g] = __builtin_amdgcn_mfma_f32_16x16x32_bf16(al0, bh, acc[0][g], 0, 0, 0);
            acc[1][g] = __builtin_amdgcn_mfma_f32_16x16x32_bf16(ah1, bh, acc[1][g], 0, 0, 0);
            acc[1][g] = __builtin_amdgcn_mfma_f32_16x16x32_bf16(ah1, bl, acc[1][g], 0, 0, 0);
            acc[1][g] = __builtin_amdgcn_mfma_f32_16x16x32_bf16(al1, bh, acc[1][g], 0, 0, 0);
        }
    }

    // epilogue: C layout col=lane&15, row=quad*4+reg
    #pragma unroll
    for (int g = 0; g < 4; ++g) {
        const int col = cb * 64 + g * 16 + m;
        const float bc = bias[col];
        #pragma unroll
        for (int tt = 0; tt < 2; ++tt) {
            #pragma unroll
            for (int r = 0; r < 4; ++r) {
                const int row = row_base + tt * 16 + q * 4 + r;
                const float v = acc[tt][g][r] + bc;
                const float vn = __shfl_xor(v, 1);   // neighbor col (lane pair)
                if (row < NV) {
                    Y[(long)row * 128 + col] = v;
                    if ((L & 1) == 0) {              // even lane stores packed pair
                        __hip_bfloat162 h2;
                        h2.x = __float2bfloat16(v);
                        h2.y = __float2bfloat16(vn);
                        *(__hip_bfloat162*)(Ybf + (long)row * 128 + col) = h2;
                    }
                }
            }
        }
    }
}

// ---------------- K2: per-hyperedge argmax pair (uvpos only) ----------------
__global__ __launch_bounds__(256) void k_edge(const float* __restrict__ Y,
                                              const int* __restrict__ vertex,
                                              int* __restrict__ uvpos) {
    __shared__ float sF[4][8 * 132];
    const int wid = threadIdx.x >> 6;
    const int lane = threadIdx.x & 63;
    const int m = blockIdx.x * 4 + wid;
    float* F = sF[wid];

    int verts[8];
    #pragma unroll
    for (int p = 0; p < 8; ++p) verts[p] = vertex[m * 8 + p];

    #pragma unroll
    for (int p = 0; p < 8; ++p) {
        const float2 v = *(const float2*)(Y + (long)verts[p] * 128 + lane * 2);
        *(float2*)(F + p * 132 + lane * 2) = v;
    }
    __syncthreads();

    const int k = lane >> 3, l = lane & 7;
    float acc = 0.0f;
    const float4* ra = (const float4*)(F + k * 132);
    const float4* rb = (const float4*)(F + l * 132);
    #pragma unroll
    for (int d4 = 0; d4 < 32; ++d4) {
        const float4 a = ra[d4], b = rb[d4];
        acc = fmaf(a.x, b.x, acc);
        acc = fmaf(a.y, b.y, acc);
        acc = fmaf(a.z, b.z, acc);
        acc = fmaf(a.w, b.w, acc);
    }
    const float sqk = __shfl(acc, k * 9);
    const float sql = __shfl(acc, l * 9);
    float v = sqk + sql - 2.0f * acc;
    int idx = lane;
    #pragma unroll
    for (int off = 32; off >= 1; off >>= 1) {
        const float ov = __shfl_xor(v, off);
        const int oi = __shfl_xor(idx, off);
        if (ov > v || (ov == v && oi < idx)) { v = ov; idx = oi; }
    }
    if (lane == 0) uvpos[m] = idx;
}

// ---------------- K2a: init cnt=0, rowptr[NV]=NINC ----------------
__global__ __launch_bounds__(256) void k_init(int* __restrict__ cnt,
                                              int* __restrict__ rowptr) {
    const int i = blockIdx.x * 256 + threadIdx.x;
    if (i < NV) cnt[i] = 0;
    if (i == 0) rowptr[NV] = NINC;
}

// ---------------- CSR build: histogram ----------------
__global__ __launch_bounds__(256) void k_hist(const int* __restrict__ vertex,
                                              int* __restrict__ cnt) {
    const int j = blockIdx.x * 256 + threadIdx.x;
    if (j < NINC) atomicAdd(cnt + vertex[j], 1);
}

// ---------------- CSR build: scan stage 1 (per-block sums) ----------------
__global__ __launch_bounds__(256) void k_scan1(const int* __restrict__ cnt,
                                               int* __restrict__ bsum) {
    __shared__ int s[256];
    const int t = threadIdx.x;
    const int i = blockIdx.x * 256 + t;
    s[t] = (i < NV) ? cnt[i] : 0;
    __syncthreads();
    #pragma unroll
    for (int off = 128; off >= 1; off >>= 1) {
        if (t < off) s[t] += s[t + off];
        __syncthreads();
    }
    if (t == 0) bsum[blockIdx.x] = s[0];
}

// ---------------- CSR build: scan stage 2 (exclusive scan of block sums) ---
__global__ __launch_bounds__(64) void k_scan2(const int* __restrict__ bsum,
                                              int* __restrict__ boff) {
    const int lane = threadIdx.x;   // single wave
    int running = 0;
    for (int c = 0; c * 64 < NBLK; ++c) {
        const int idx = c * 64 + lane;
        int v = (idx < NBLK) ? bsum[idx] : 0;
        int x = v;
        #pragma unroll
        for (int off = 1; off < 64; off <<= 1) {
            const int n = __shfl_up(x, off);
            if (lane >= off) x += n;
        }
        if (idx < NBLK) boff[idx] = running + x - v;   // exclusive
        running += __shfl(x, 63);
    }
}

// ---------------- CSR build: scan stage 3 (rowptr + fill ptr) ----------------
__global__ __launch_bounds__(256) void k_scan3(const int* __restrict__ cnt,
                                               const int* __restrict__ boff,
                                               int* __restrict__ rowptr,
                                               int* __restrict__ fill) {
    __shared__ int s[256];
    const int t = threadIdx.x;
    const int i = blockIdx.x * 256 + t;
    const int v = (i < NV) ? cnt[i] : 0;
    s[t] = v;
    __syncthreads();
    #pragma unroll
    for (int off = 1; off < 256; off <<= 1) {
        const int add = (t >= off) ? s[t - off] : 0;
        __syncthreads();
        s[t] += add;
        __syncthreads();
    }
    if (i < NV) {
        const int excl = boff[blockIdx.x] + s[t] - v;
        rowptr[i] = excl;
        fill[i] = excl;
    }
}

// ---------------- CSR build: fill entries with (m<<1)|role ----------------
__global__ __launch_bounds__(256) void k_fill(const int* __restrict__ vertex,
                                              const int* __restrict__ uvpos,
                                              int* __restrict__ fill,
                                              int* __restrict__ entries) {
    const int j = blockIdx.x * 256 + threadIdx.x;
    if (j < NINC) {
        const int v = vertex[j];
        const int m = j >> 3, p = j & 7;
        const int idx = uvpos[m];
        const int role = (p == (idx >> 3) || p == (idx & 7)) ? 0 : 1;
        const int slot = atomicAdd(fill + v, 1);
        entries[slot] = (m << 1) | role;
    }
}

// ---------------- K3: exact per-vertex degree (no atomics) ----------------
__global__ __launch_bounds__(256) void k_deg(const int* __restrict__ rowptr,
                                             const int* __restrict__ entries,
                                             float* __restrict__ deg) {
    const int i = blockIdx.x * 256 + threadIdx.x;
    if (i >= NV) return;
    const int start = rowptr[i], end = rowptr[i + 1];
    float d = 1.0f;
    for (int e = start; e < end; ++e)
        d += (entries[e] & 1) ? (2.0f * WMED) : (7.0f * WMED);
    deg[i] = d;
}

// ---------------- K4: per-edge w*S, w*P rows (reads bf16 Y copy) ----------
__global__ __launch_bounds__(256) void k_sp(const __hip_bfloat16* __restrict__ Ybf,
                                            const int* __restrict__ vertex,
                                            const int* __restrict__ uvpos,
                                            const float* __restrict__ deg,
                                            __hip_bfloat162* __restrict__ SP) {
    const int wid = threadIdx.x >> 6;
    const int lane = threadIdx.x & 63;
    const int m = blockIdx.x * 4 + wid;

    const int idx = uvpos[m];
    const int ui = idx >> 3, vi = idx & 7;

    float S0 = 0.f, S1 = 0.f, U0 = 0.f, U1 = 0.f, V0 = 0.f, V1 = 0.f;
    #pragma unroll
    for (int p = 0; p < 8; ++p) {
        const int vp = vertex[m * 8 + p];
        const float di = rsqrtf(deg[vp]);
        const __hip_bfloat162 y2 =
            ((const __hip_bfloat162*)(Ybf + (long)vp * 128))[lane];
        const float r0 = __bfloat162float(y2.x) * di;
        const float r1 = __bfloat162float(y2.y) * di;
        S0 += r0; S1 += r1;
        if (p == ui) { U0 = r0; U1 = r1; }
        if (p == vi) { V0 = r0; V1 = r1; }
    }
    __hip_bfloat162 s2, p2;
    s2.x = __float2bfloat16(WMED * S0);
    s2.y = __float2bfloat16(WMED * S1);
    p2.x = __float2bfloat16(WMED * (U0 + V0));
    p2.y = __float2bfloat16(WMED * (U1 + V1));
    SP[(long)(2 * m) * 64 + lane] = s2;        // S row
    SP[(long)(2 * m + 1) * 64 + lane] = p2;    // P row
}

// ---------------- K5: per-vertex gather: one bf16 row per incidence --------
// R1: one lane-indexed load fetches the whole entry row; t's via __shfl;
// SP rows load 4-wide independent per chunk (masked-duplicate remainder).
__global__ __launch_bounds__(256) void k_gather(const float* __restrict__ Y,
                                                const float* __restrict__ deg,
                                                const int* __restrict__ rowptr,
                                                const int* __restrict__ entries,
                                                const __hip_bfloat162* __restrict__ SP,
                                                float* __restrict__ out) {
    const int wid = threadIdx.x >> 6;
    const int lane = threadIdx.x & 63;
    const int i = blockIdx.x * 4 + wid;

    const int start = rowptr[i], end = rowptr[i + 1];
    const int degc = end - start;
    // one coalesced load grabs all entries of this row
    const int tl = (lane < degc) ? entries[start + lane] : 0;

    const float din = rsqrtf(deg[i]);
    const float2 y = *(const float2*)(Y + (long)i * 128 + lane * 2);
    const float xs0 = y.x * din;
    const float xs1 = y.y * din;

    float a0 = 0.f, a1 = 0.f;
    float fnuv = 0.f;
    const int dmain = (degc < 64) ? degc : 64;

    for (int e = 0; e < dmain; e += 4) {
        const int j1 = (e + 1 < dmain) ? e + 1 : e;
        const int j2 = (e + 2 < dmain) ? e + 2 : e;
        const int j3 = (e + 3 < dmain) ? e + 3 : e;
        const float m1 = (e + 1 < dmain) ? 1.f : 0.f;
        const float m2 = (e + 2 < dmain) ? 1.f : 0.f;
        const float m3 = (e + 3 < dmain) ? 1.f : 0.f;
        const int t0 = __shfl(tl, e);
        const int t1 = __shfl(tl, j1);
        const int t2 = __shfl(tl, j2);
        const int t3 = __shfl(tl, j3);
        // 4 independent 256B row loads issue back-to-back
        const __hip_bfloat162 T0 = SP[(long)t0 * 64 + lane];
        const __hip_bfloat162 T1 = SP[(long)t1 * 64 + lane];
        const __hip_bfloat162 T2 = SP[(long)t2 * 64 + lane];
        const __hip_bfloat162 T3 = SP[(long)t3 * 64 + lane];
        fnuv += (float)((t0 & 1) ^ 1) + m1 * (float)((t1 & 1) ^ 1)
              + m2 * (float)((t2 & 1) ^ 1) + m3 * (float)((t3 & 1) ^ 1);
        a0 += __bfloat162float(T0.x) + m1 * __bfloat162float(T1.x)
            + m2 * __bfloat162float(T2.x) + m3 * __bfloat162float(T3.x);
        a1 += __bfloat162float(T0.y) + m1 * __bfloat162float(T1.y)
            + m2 * __bfloat162float(T2.y) + m3 * __bfloat162float(T3.y);
    }
    // pathological overflow (deg > 64): serial fallback, essentially never taken
    for (int e2 = start + 64; e2 < end; ++e2) {
        const int t = entries[e2];
        const __hip_bfloat162 T = SP[(long)t * 64 + lane];
        fnuv += (float)((t & 1) ^ 1);
        a0 += __bfloat162float(T.x);
        a1 += __bfloat162float(T.y);
    }

    const float self = 1.0f - WMED * fnuv;
    a0 = fmaf(self, xs0, a0);
    a1 = fmaf(self, xs1, a1);
    float2 o;
    o.x = fmaxf(a0 * din, 0.0f);
    o.y = fmaxf(a1 * din, 0.0f);
    *(float2*)(out + (long)i * 128 + lane * 2) = o;
}

extern "C" void kernel_launch(void* const* d_in, const int* in_sizes, int n_in,
                              void* d_out, int out_size, void* d_ws, size_t ws_size,
                              hipStream_t stream) {
    const float* X      = (const float*)d_in[0];   // [N,128]
    const int*   vertex = (const int*)d_in[1];     // [M*8]
    // d_in[2] = edges (repeat(arange(M),8)) -- unused
    const float* W      = (const float*)d_in[3];   // [128,128]
    const float* bias   = (const float*)d_in[4];   // [128]
    float* out = (float*)d_out;                    // [N,128]

    // workspace: Y[N*128] f32 | Ybf[N*128] bf16 | SP[2M*128] bf16 | deg[N] |
    //            uvpos[M] | cnt[N] | rowptr[N+1] | fill[N] | bsum | boff |
    //            entries | Wg (pre-split W frags, 64 KB, 16B-aligned)
    float* Y              = (float*)d_ws;
    __hip_bfloat16* Ybf   = (__hip_bfloat16*)(Y + (long)NV * 128);
    __hip_bfloat162* SP   = (__hip_bfloat162*)(Ybf + (long)NV * 128);
    float* deg            = (float*)((__hip_bfloat16*)SP + (long)2 * ME * 128);
    int*   uvpos          = (int*)(deg + NV);
    int*   cnt            = uvpos + ME;
    int*   rowptr         = cnt + NV;
    int*   fill           = rowptr + NV + 1;
    int*   bsum           = fill + NV;
    int*   boff           = bsum + NBLK;
    int*   entries        = boff + NBLK;
    char*  pW             = (char*)(entries + NINC);
    uint4* Wg             = (uint4*)(((uintptr_t)pW + 15) & ~(uintptr_t)15);

    k_wsplit<<<64, 256, 0, stream>>>(W, (short*)Wg);
    k_gemm <<<NBLK * 2, 512, 0, stream>>>(X, Wg, bias, Y, Ybf);
    k_edge <<<ME / 4, 256, 0, stream>>>(Y, vertex, uvpos);
    k_init <<<NBLK, 256, 0, stream>>>(cnt, rowptr);
    k_hist <<<(NINC + 255) / 256, 256, 0, stream>>>(vertex, cnt);
    k_scan1<<<NBLK, 256, 0, stream>>>(cnt, bsum);
    k_scan2<<<1, 64, 0, stream>>>(bsum, boff);
    k_scan3<<<NBLK, 256, 0, stream>>>(cnt, boff, rowptr, fill);
    k_fill <<<(NINC + 255) / 256, 256, 0, stream>>>(vertex, uvpos, fill, entries);
    k_deg  <<<NBLK, 256, 0, stream>>>(rowptr, entries, deg);
    k_sp   <<<ME / 4, 256, 0, stream>>>(Ybf, vertex, uvpos, deg, SP);
    k_gather<<<NV / 4, 256, 0, stream>>>(Y, deg, rowptr, entries, SP, out);
}